// Round 3
// baseline (85.776 us; speedup 1.0000x reference)
//
#include <hip/hip_runtime.h>

namespace {
constexpr int DIM = 16;       // 2^4 qubits
constexpr int BATCH = 8;
constexpr int H = 96, W = 96, CH = 16;
constexpr int OH = 95, OW = 95;
constexpr int NF = 8, NW = 24;
constexpr int NPIX = BATCH * OH * OW;        // 72200
constexpr int PBLK = (NPIX + 255) / 256;     // 283
constexpr int PSI_OFF = NF * 512;            // float offset of psi region in ws
}

// ---------------- K1a: build per-filter 16x16 complex unitary ----------------
// thread (f=blockIdx.x, col=threadIdx.x): apply circuit to e_col, store column.
__global__ void build_u_kernel(const float* __restrict__ wts, float* __restrict__ ws) {
  const int f = blockIdx.x;
  const int col = threadIdx.x;   // 0..15
  const float* w = wts + f * NW;

  float ar[DIM], ai[DIM];
#pragma unroll
  for (int i = 0; i < DIM; ++i) { ar[i] = (i == col) ? 1.f : 0.f; ai[i] = 0.f; }

#pragma unroll
  for (int layer = 0; layer < 2; ++layer) {
    const int wb = layer * 12;
#pragma unroll
    for (int q = 0; q < 4; ++q) {
      const int m = 8 >> q;
      float c, s;
      {  // RX: [[c,-is],[-is,c]]
        __sincosf(w[wb + q * 3] * 0.5f, &s, &c);
#pragma unroll
        for (int i = 0; i < DIM; ++i) {
          if (i & m) continue;
          const int j = i | m;
          const float a0r = ar[i], a0i = ai[i], a1r = ar[j], a1i = ai[j];
          ar[i] = fmaf(c, a0r,  s * a1i);
          ai[i] = fmaf(c, a0i, -s * a1r);
          ar[j] = fmaf(c, a1r,  s * a0i);
          ai[j] = fmaf(c, a1i, -s * a0r);
        }
      }
      {  // RY: [[c,-s],[s,c]]
        __sincosf(w[wb + q * 3 + 1] * 0.5f, &s, &c);
#pragma unroll
        for (int i = 0; i < DIM; ++i) {
          if (i & m) continue;
          const int j = i | m;
          const float a0r = ar[i], a0i = ai[i], a1r = ar[j], a1i = ai[j];
          ar[i] = fmaf(c, a0r, -s * a1r);
          ai[i] = fmaf(c, a0i, -s * a1i);
          ar[j] = fmaf(s, a0r,  c * a1r);
          ai[j] = fmaf(s, a0i,  c * a1i);
        }
      }
      {  // RZ: diag(c-is, c+is)
        __sincosf(w[wb + q * 3 + 2] * 0.5f, &s, &c);
#pragma unroll
        for (int i = 0; i < DIM; ++i) {
          const float r = ar[i], im = ai[i];
          if (i & m) { ar[i] = fmaf(c, r, -s * im); ai[i] = fmaf(c, im,  s * r); }
          else       { ar[i] = fmaf(c, r,  s * im); ai[i] = fmaf(c, im, -s * r); }
        }
      }
    }
    {  // CRY(w[wb+0], ctrl bit8, tgt bit4)
      float c, s;
      __sincosf(w[wb + 0] * 0.5f, &s, &c);
#pragma unroll
      for (int i = 0; i < DIM; ++i) {
        if (!(i & 8) || (i & 4)) continue;
        const int j = i | 4;
        const float a0r = ar[i], a0i = ai[i], a1r = ar[j], a1i = ai[j];
        ar[i] = fmaf(c, a0r, -s * a1r);
        ai[i] = fmaf(c, a0i, -s * a1i);
        ar[j] = fmaf(s, a0r,  c * a1r);
        ai[j] = fmaf(s, a0i,  c * a1i);
      }
    }
    {  // CRY(w[wb+2], ctrl bit2, tgt bit1)
      float c, s;
      __sincosf(w[wb + 2] * 0.5f, &s, &c);
#pragma unroll
      for (int i = 0; i < DIM; ++i) {
        if (!(i & 2) || (i & 1)) continue;
        const int j = i | 1;
        const float a0r = ar[i], a0i = ai[i], a1r = ar[j], a1i = ai[j];
        ar[i] = fmaf(c, a0r, -s * a1r);
        ai[i] = fmaf(c, a0i, -s * a1i);
        ar[j] = fmaf(s, a0r,  c * a1r);
        ai[j] = fmaf(s, a0i,  c * a1i);
      }
    }
  }

  // column-major store: U[f][k=col][i] real at +i, imag at +16+i
  float* dst = ws + f * 512 + col * 32;
#pragma unroll
  for (int i = 0; i < DIM; ++i) { dst[i] = ar[i]; dst[16 + i] = ai[i]; }
}

// ---------------- K1b: per-patch real initial state psi0 ----------------
__global__ __launch_bounds__(256)
void psi_kernel(const float* __restrict__ x, float* __restrict__ ws) {
  const int n = blockIdx.x * 256 + threadIdx.x;
  if (n >= NPIX) return;
  const int b = n / (OH * OW);
  const int rem = n - b * (OH * OW);
  const int oi = rem / OW;
  const int oj = rem - oi * OW;

  const float* base = x + (((b * H) + oi) * W + oj) * CH;
  float ss = 0.f;
  float4 f0 = make_float4(0.f, 0.f, 0.f, 0.f);
#pragma unroll
  for (int fi = 0; fi < 2; ++fi) {
    const float4* row = reinterpret_cast<const float4*>(base + fi * W * CH);
#pragma unroll
    for (int k = 0; k < 8; ++k) {
      const float4 v = row[k];
      if (fi == 0 && k == 0) f0 = v;
      ss = fmaf(v.x, v.x, ss); ss = fmaf(v.y, v.y, ss);
      ss = fmaf(v.z, v.z, ss); ss = fmaf(v.w, v.w, ss);
    }
  }
  const float inv = rsqrtf(fmaxf(ss, 1e-12f));

  float cq[4], sq[4];
  __sincosf(f0.x * inv * 0.5f, &sq[0], &cq[0]);
  __sincosf(f0.y * inv * 0.5f, &sq[1], &cq[1]);
  __sincosf(f0.z * inv * 0.5f, &sq[2], &cq[2]);
  __sincosf(f0.w * inv * 0.5f, &sq[3], &cq[3]);

  // product state with CNOT chain permutation baked in:
  // j = i; if(j&8) j^=4; if(j&4) j^=2; if(j&2) j^=1; st[j] = prod(i)
  float st[DIM];
#pragma unroll
  for (int i = 0; i < DIM; ++i) {
    const float pr = ((i & 8) ? sq[0] : cq[0]) * ((i & 4) ? sq[1] : cq[1]) *
                     ((i & 2) ? sq[2] : cq[2]) * ((i & 1) ? sq[3] : cq[3]);
    int j = i;
    if (j & 8) j ^= 4;
    if (j & 4) j ^= 2;
    if (j & 2) j ^= 1;
    st[j] = pr;
  }

  float4* dst = reinterpret_cast<float4*>(ws + PSI_OFF + n * 16);
  dst[0] = make_float4(st[0], st[1], st[2], st[3]);
  dst[1] = make_float4(st[4], st[5], st[6], st[7]);
  dst[2] = make_float4(st[8], st[9], st[10], st[11]);
  dst[3] = make_float4(st[12], st[13], st[14], st[15]);
}

// ---------------- K2: y = U_f psi0, weighted |y|^2 reduce ----------------
__global__ __launch_bounds__(256)
void apply_kernel(const float* __restrict__ ws, float* __restrict__ out) {
  __shared__ float U[512];
  const int tid = threadIdx.x;
  const int f = blockIdx.y;
  if (tid < 128)
    reinterpret_cast<float4*>(U)[tid] =
        reinterpret_cast<const float4*>(ws + f * 512)[tid];
  __syncthreads();

  const int n = blockIdx.x * 256 + tid;
  const bool valid = n < NPIX;
  const int nc = valid ? n : NPIX - 1;

  float psi[DIM];
  {
    const float4* pp = reinterpret_cast<const float4*>(ws + PSI_OFF + nc * 16);
    const float4 a = pp[0], b4 = pp[1], c4 = pp[2], d4 = pp[3];
    psi[0] = a.x;  psi[1] = a.y;  psi[2] = a.z;  psi[3] = a.w;
    psi[4] = b4.x; psi[5] = b4.y; psi[6] = b4.z; psi[7] = b4.w;
    psi[8] = c4.x; psi[9] = c4.y; psi[10] = c4.z; psi[11] = c4.w;
    psi[12] = d4.x; psi[13] = d4.y; psi[14] = d4.z; psi[15] = d4.w;
  }

  float yr[DIM], yi[DIM];
#pragma unroll
  for (int i = 0; i < DIM; ++i) { yr[i] = 0.f; yi[i] = 0.f; }

  const float4* l4 = reinterpret_cast<const float4*>(U);
#define FMA4(dst, d0, v)                      \
  dst[d0 + 0] = fmaf((v).x, pk, dst[d0 + 0]); \
  dst[d0 + 1] = fmaf((v).y, pk, dst[d0 + 1]); \
  dst[d0 + 2] = fmaf((v).z, pk, dst[d0 + 2]); \
  dst[d0 + 3] = fmaf((v).w, pk, dst[d0 + 3]);
#pragma unroll
  for (int k = 0; k < DIM; ++k) {
    const float pk = psi[k];
    const float4 r0 = l4[k * 8 + 0], r1 = l4[k * 8 + 1];
    const float4 r2 = l4[k * 8 + 2], r3 = l4[k * 8 + 3];
    const float4 i0 = l4[k * 8 + 4], i1 = l4[k * 8 + 5];
    const float4 i2 = l4[k * 8 + 6], i3 = l4[k * 8 + 7];
    FMA4(yr, 0, r0) FMA4(yr, 4, r1) FMA4(yr, 8, r2) FMA4(yr, 12, r3)
    FMA4(yi, 0, i0) FMA4(yi, 4, i1) FMA4(yi, 8, i2) FMA4(yi, 12, i3)
  }
#undef FMA4

  float p[DIM];
#pragma unroll
  for (int i = 0; i < DIM; ++i) p[i] = fmaf(yr[i], yr[i], yi[i] * yi[i]);
  const float acc = (p[0] - p[15]) +
                    0.5f * ((p[1] + p[2] + p[4] + p[8]) -
                            (p[7] + p[11] + p[13] + p[14]));
  if (valid) out[nc * NF + f] = acc;
}

extern "C" void kernel_launch(void* const* d_in, const int* in_sizes, int n_in,
                              void* d_out, int out_size, void* d_ws, size_t ws_size,
                              hipStream_t stream) {
  const float* x = (const float*)d_in[0];
  const float* w = (const float*)d_in[1];
  float* out = (float*)d_out;
  float* ws = (float*)d_ws;

  build_u_kernel<<<dim3(NF), dim3(DIM), 0, stream>>>(w, ws);
  psi_kernel<<<dim3(PBLK), dim3(256), 0, stream>>>(x, ws);
  apply_kernel<<<dim3(PBLK, NF), dim3(256), 0, stream>>>(ws, out);
}

// Round 4
// 78.032 us; speedup vs baseline: 1.0992x; 1.0992x over previous
//
#include <hip/hip_runtime.h>

namespace {
constexpr int DIM = 16;
constexpr int BATCH = 8;
constexpr int H = 96, W = 96, CH = 16;
constexpr int OH = 95, OW = 95;
constexpr int NF = 8, NW = 24;
constexpr int NPIX = BATCH * OH * OW;          // 72200
constexpr int PSIBLK = (NPIX + 255) / 256;     // 283 psi blocks; block PSIBLK builds M
constexpr int M_FLOATS = NF * 256;             // 2048
constexpr int PSI_OFF = M_FLOATS;              // psi region starts at 8KB
constexpr int PPB = 32;                        // patches per apply block
constexpr int APBLK = (NPIX + PPB - 1) / PPB;  // 2257
constexpr int MPAD = 260;                      // LDS row stride (floats): f*260*4B spreads banks
}

__device__ __forceinline__ int permf(int i) {
  int j = i;
  if (j & 8) j ^= 4;
  if (j & 4) j ^= 2;
  if (j & 2) j ^= 1;
  return j;
}

// K1: blocks 0..PSIBLK-1 compute per-patch product state psi; block PSIBLK builds M_f.
__global__ __launch_bounds__(256)
void prep_kernel(const float* __restrict__ x, const float* __restrict__ wts,
                 float* __restrict__ ws) {
  const int tid = threadIdx.x;
  if (blockIdx.x == PSIBLK) {
    // ---------- build M_f = Re(U_f^H Z U_f), CNOT perm baked ----------
    __shared__ float ur[NF * 256];
    __shared__ float ui[NF * 256];
    const int f = tid >> 4;
    const int col = tid & 15;
    if (tid < NF * DIM) {
      const float* w = wts + f * NW;
      float ar[DIM], ai[DIM];
#pragma unroll
      for (int i = 0; i < DIM; ++i) { ar[i] = (i == col) ? 1.f : 0.f; ai[i] = 0.f; }
#pragma unroll
      for (int layer = 0; layer < 2; ++layer) {
        const int wb = layer * 12;
#pragma unroll
        for (int q = 0; q < 4; ++q) {
          const int m = 8 >> q;
          float c, s;
          {  // RX
            __sincosf(w[wb + q * 3] * 0.5f, &s, &c);
#pragma unroll
            for (int i = 0; i < DIM; ++i) {
              if (i & m) continue;
              const int j = i | m;
              const float a0r = ar[i], a0i = ai[i], a1r = ar[j], a1i = ai[j];
              ar[i] = fmaf(c, a0r,  s * a1i);
              ai[i] = fmaf(c, a0i, -s * a1r);
              ar[j] = fmaf(c, a1r,  s * a0i);
              ai[j] = fmaf(c, a1i, -s * a0r);
            }
          }
          {  // RY
            __sincosf(w[wb + q * 3 + 1] * 0.5f, &s, &c);
#pragma unroll
            for (int i = 0; i < DIM; ++i) {
              if (i & m) continue;
              const int j = i | m;
              const float a0r = ar[i], a0i = ai[i], a1r = ar[j], a1i = ai[j];
              ar[i] = fmaf(c, a0r, -s * a1r);
              ai[i] = fmaf(c, a0i, -s * a1i);
              ar[j] = fmaf(s, a0r,  c * a1r);
              ai[j] = fmaf(s, a0i,  c * a1i);
            }
          }
          {  // RZ
            __sincosf(w[wb + q * 3 + 2] * 0.5f, &s, &c);
#pragma unroll
            for (int i = 0; i < DIM; ++i) {
              const float r = ar[i], im = ai[i];
              if (i & m) { ar[i] = fmaf(c, r, -s * im); ai[i] = fmaf(c, im,  s * r); }
              else       { ar[i] = fmaf(c, r,  s * im); ai[i] = fmaf(c, im, -s * r); }
            }
          }
        }
        {  // CRY(ctrl bit8, tgt bit4)
          float c, s;
          __sincosf(w[wb + 0] * 0.5f, &s, &c);
#pragma unroll
          for (int i = 0; i < DIM; ++i) {
            if (!(i & 8) || (i & 4)) continue;
            const int j = i | 4;
            const float a0r = ar[i], a0i = ai[i], a1r = ar[j], a1i = ai[j];
            ar[i] = fmaf(c, a0r, -s * a1r);
            ai[i] = fmaf(c, a0i, -s * a1i);
            ar[j] = fmaf(s, a0r,  c * a1r);
            ai[j] = fmaf(s, a0i,  c * a1i);
          }
        }
        {  // CRY(ctrl bit2, tgt bit1)
          float c, s;
          __sincosf(w[wb + 2] * 0.5f, &s, &c);
#pragma unroll
          for (int i = 0; i < DIM; ++i) {
            if (!(i & 2) || (i & 1)) continue;
            const int j = i | 1;
            const float a0r = ar[i], a0i = ai[i], a1r = ar[j], a1i = ai[j];
            ar[i] = fmaf(c, a0r, -s * a1r);
            ai[i] = fmaf(c, a0i, -s * a1i);
            ar[j] = fmaf(s, a0r,  c * a1r);
            ai[j] = fmaf(s, a0i,  c * a1i);
          }
        }
      }
      // ur[f][col][i] = U_{i,col}
#pragma unroll
      for (int i = 0; i < DIM; ++i) {
        ur[f * 256 + col * 16 + i] = ar[i];
        ui[f * 256 + col * 16 + i] = ai[i];
      }
    }
    __syncthreads();
    if (tid < NF * DIM) {
      const int k = col;
      const int pk = permf(k);
      const float* cr = ur + f * 256;
      const float* ci = ui + f * 256;
      float* dst = ws + f * 256 + k * 16;  // row k of Mp[f]
#pragma unroll
      for (int j = 0; j < DIM; ++j) {
        const int pj = permf(j);
        float acc = 0.f;
#pragma unroll
        for (int i = 0; i < DIM; ++i) {
          const float z = 1.f - 0.5f * (float)__popc(i);
          acc += z * (cr[pk * 16 + i] * cr[pj * 16 + i] +
                      ci[pk * 16 + i] * ci[pj * 16 + i]);
        }
        dst[j] = acc;
      }
    }
  } else {
    // ---------- per-patch product state (post-RY, pre-perm) ----------
    const int n = blockIdx.x * 256 + tid;
    if (n >= NPIX) return;
    const int b = n / (OH * OW);
    const int rem = n - b * (OH * OW);
    const int oi = rem / OW;
    const int oj = rem - oi * OW;

    const float* base = x + (((b * H) + oi) * W + oj) * CH;
    float ss = 0.f;
    float4 f0 = make_float4(0.f, 0.f, 0.f, 0.f);
#pragma unroll
    for (int fi = 0; fi < 2; ++fi) {
      const float4* row = reinterpret_cast<const float4*>(base + fi * W * CH);
#pragma unroll
      for (int k = 0; k < 8; ++k) {
        const float4 v = row[k];
        if (fi == 0 && k == 0) f0 = v;
        ss = fmaf(v.x, v.x, ss); ss = fmaf(v.y, v.y, ss);
        ss = fmaf(v.z, v.z, ss); ss = fmaf(v.w, v.w, ss);
      }
    }
    const float inv = rsqrtf(fmaxf(ss, 1e-12f));

    float cq[4], sq[4];
    __sincosf(f0.x * inv * 0.5f, &sq[0], &cq[0]);
    __sincosf(f0.y * inv * 0.5f, &sq[1], &cq[1]);
    __sincosf(f0.z * inv * 0.5f, &sq[2], &cq[2]);
    __sincosf(f0.w * inv * 0.5f, &sq[3], &cq[3]);

    float st[DIM];
#pragma unroll
    for (int i = 0; i < DIM; ++i) {
      st[i] = ((i & 8) ? sq[0] : cq[0]) * ((i & 4) ? sq[1] : cq[1]) *
              ((i & 2) ? sq[2] : cq[2]) * ((i & 1) ? sq[3] : cq[3]);
    }
    float4* dst = reinterpret_cast<float4*>(ws + PSI_OFF + n * 16);
    dst[0] = make_float4(st[0], st[1], st[2], st[3]);
    dst[1] = make_float4(st[4], st[5], st[6], st[7]);
    dst[2] = make_float4(st[8], st[9], st[10], st[11]);
    dst[3] = make_float4(st[12], st[13], st[14], st[15]);
  }
}

// K2: out[n, f] = psi_n^T Mp_f psi_n.  Block = 32 patches x 8 filters.
__global__ __launch_bounds__(256)
void apply_kernel(const float* __restrict__ ws, float* __restrict__ out) {
  __shared__ float M[NF * MPAD];  // padded: row stride 260 floats -> conflict-free
  const int tid = threadIdx.x;
#pragma unroll
  for (int it = 0; it < 2; ++it) {
    const int i = it * 256 + tid;  // 0..511 float4s
    const int ff = i >> 6;
    const int r = i & 63;
    reinterpret_cast<float4*>(M + ff * MPAD)[r] =
        reinterpret_cast<const float4*>(ws)[i];
  }
  __syncthreads();

  const int p = tid >> 3;
  const int f = tid & 7;
  const int n = blockIdx.x * PPB + p;
  const bool valid = n < NPIX;
  const int nc = valid ? n : NPIX - 1;

  float psi[DIM];
  {
    const float4* pp = reinterpret_cast<const float4*>(ws + PSI_OFF + nc * 16);
    const float4 a0 = pp[0], a1 = pp[1], a2 = pp[2], a3 = pp[3];
    psi[0] = a0.x;  psi[1] = a0.y;  psi[2] = a0.z;  psi[3] = a0.w;
    psi[4] = a1.x;  psi[5] = a1.y;  psi[6] = a1.z;  psi[7] = a1.w;
    psi[8] = a2.x;  psi[9] = a2.y;  psi[10] = a2.z; psi[11] = a2.w;
    psi[12] = a3.x; psi[13] = a3.y; psi[14] = a3.z; psi[15] = a3.w;
  }

  float yv[DIM];
#pragma unroll
  for (int i = 0; i < DIM; ++i) yv[i] = 0.f;

  const float4* mrow = reinterpret_cast<const float4*>(M + f * MPAD);
#pragma unroll
  for (int k = 0; k < DIM; ++k) {
    const float t = psi[k];
    const float4 m0 = mrow[k * 4 + 0];
    const float4 m1 = mrow[k * 4 + 1];
    const float4 m2 = mrow[k * 4 + 2];
    const float4 m3 = mrow[k * 4 + 3];
    yv[0]  = fmaf(m0.x, t, yv[0]);  yv[1]  = fmaf(m0.y, t, yv[1]);
    yv[2]  = fmaf(m0.z, t, yv[2]);  yv[3]  = fmaf(m0.w, t, yv[3]);
    yv[4]  = fmaf(m1.x, t, yv[4]);  yv[5]  = fmaf(m1.y, t, yv[5]);
    yv[6]  = fmaf(m1.z, t, yv[6]);  yv[7]  = fmaf(m1.w, t, yv[7]);
    yv[8]  = fmaf(m2.x, t, yv[8]);  yv[9]  = fmaf(m2.y, t, yv[9]);
    yv[10] = fmaf(m2.z, t, yv[10]); yv[11] = fmaf(m2.w, t, yv[11]);
    yv[12] = fmaf(m3.x, t, yv[12]); yv[13] = fmaf(m3.y, t, yv[13]);
    yv[14] = fmaf(m3.z, t, yv[14]); yv[15] = fmaf(m3.w, t, yv[15]);
  }

  float s0 = 0.f, s1 = 0.f, s2 = 0.f, s3 = 0.f;
#pragma unroll
  for (int i = 0; i < DIM; i += 4) {
    s0 = fmaf(psi[i + 0], yv[i + 0], s0);
    s1 = fmaf(psi[i + 1], yv[i + 1], s1);
    s2 = fmaf(psi[i + 2], yv[i + 2], s2);
    s3 = fmaf(psi[i + 3], yv[i + 3], s3);
  }
  if (valid) out[blockIdx.x * 256 + tid] = (s0 + s1) + (s2 + s3);
}

extern "C" void kernel_launch(void* const* d_in, const int* in_sizes, int n_in,
                              void* d_out, int out_size, void* d_ws, size_t ws_size,
                              hipStream_t stream) {
  const float* x = (const float*)d_in[0];
  const float* w = (const float*)d_in[1];
  float* out = (float*)d_out;
  float* ws = (float*)d_ws;

  prep_kernel<<<dim3(PSIBLK + 1), dim3(256), 0, stream>>>(x, w, ws);
  apply_kernel<<<dim3(APBLK), dim3(256), 0, stream>>>(ws, out);
}

// Round 6
// 76.598 us; speedup vs baseline: 1.1198x; 1.0187x over previous
//
#include <hip/hip_runtime.h>

namespace {
constexpr int DIM = 16;
constexpr int BATCH = 8;
constexpr int H = 96, W = 96, CH = 16;
constexpr int OH = 95, OW = 95;
constexpr int NF = 8, NW = 24;
constexpr int NPIX = BATCH * OH * OW;          // 72200
constexpr int PSIBLK = (NPIX + 255) / 256;     // 283; block PSIBLK builds M
constexpr int PSI_OFF = NF * 256;              // M = 2048 floats, then psi
constexpr int PPB = 128;                       // patches per apply block (64 lanes x 2)
constexpr int ABLK = (NPIX + PPB - 1) / PPB;   // 565
}

__device__ __forceinline__ int permf(int i) {
  int j = i;
  if (j & 8) j ^= 4;
  if (j & 4) j ^= 2;
  if (j & 2) j ^= 1;
  return j;
}

// K1: blocks 0..PSIBLK-1 -> per-patch product state psi; block PSIBLK -> M_f.
__global__ __launch_bounds__(256)
void prep_kernel(const float* __restrict__ x, const float* __restrict__ wts,
                 float* __restrict__ ws) {
  const int tid = threadIdx.x;
  if (blockIdx.x == PSIBLK) {
    __shared__ float ur[NF * 256];
    __shared__ float ui[NF * 256];
    const int f = tid >> 4;
    const int col = tid & 15;
    if (tid < NF * DIM) {
      const float* w = wts + f * NW;
      float ar[DIM], ai[DIM];
#pragma unroll
      for (int i = 0; i < DIM; ++i) { ar[i] = (i == col) ? 1.f : 0.f; ai[i] = 0.f; }
#pragma unroll
      for (int layer = 0; layer < 2; ++layer) {
        const int wb = layer * 12;
#pragma unroll
        for (int q = 0; q < 4; ++q) {
          const int m = 8 >> q;
          float c, s;
          {  // RX
            __sincosf(w[wb + q * 3] * 0.5f, &s, &c);
#pragma unroll
            for (int i = 0; i < DIM; ++i) {
              if (i & m) continue;
              const int j = i | m;
              const float a0r = ar[i], a0i = ai[i], a1r = ar[j], a1i = ai[j];
              ar[i] = fmaf(c, a0r,  s * a1i);
              ai[i] = fmaf(c, a0i, -s * a1r);
              ar[j] = fmaf(c, a1r,  s * a0i);
              ai[j] = fmaf(c, a1i, -s * a0r);
            }
          }
          {  // RY
            __sincosf(w[wb + q * 3 + 1] * 0.5f, &s, &c);
#pragma unroll
            for (int i = 0; i < DIM; ++i) {
              if (i & m) continue;
              const int j = i | m;
              const float a0r = ar[i], a0i = ai[i], a1r = ar[j], a1i = ai[j];
              ar[i] = fmaf(c, a0r, -s * a1r);
              ai[i] = fmaf(c, a0i, -s * a1i);
              ar[j] = fmaf(s, a0r,  c * a1r);
              ai[j] = fmaf(s, a0i,  c * a1i);
            }
          }
          {  // RZ
            __sincosf(w[wb + q * 3 + 2] * 0.5f, &s, &c);
#pragma unroll
            for (int i = 0; i < DIM; ++i) {
              const float r = ar[i], im = ai[i];
              if (i & m) { ar[i] = fmaf(c, r, -s * im); ai[i] = fmaf(c, im,  s * r); }
              else       { ar[i] = fmaf(c, r,  s * im); ai[i] = fmaf(c, im, -s * r); }
            }
          }
        }
        {  // CRY(ctrl bit8, tgt bit4)
          float c, s;
          __sincosf(w[wb + 0] * 0.5f, &s, &c);
#pragma unroll
          for (int i = 0; i < DIM; ++i) {
            if (!(i & 8) || (i & 4)) continue;
            const int j = i | 4;
            const float a0r = ar[i], a0i = ai[i], a1r = ar[j], a1i = ai[j];
            ar[i] = fmaf(c, a0r, -s * a1r);
            ai[i] = fmaf(c, a0i, -s * a1i);
            ar[j] = fmaf(s, a0r,  c * a1r);
            ai[j] = fmaf(s, a0i,  c * a1i);
          }
        }
        {  // CRY(ctrl bit2, tgt bit1)
          float c, s;
          __sincosf(w[wb + 2] * 0.5f, &s, &c);
#pragma unroll
          for (int i = 0; i < DIM; ++i) {
            if (!(i & 2) || (i & 1)) continue;
            const int j = i | 1;
            const float a0r = ar[i], a0i = ai[i], a1r = ar[j], a1i = ai[j];
            ar[i] = fmaf(c, a0r, -s * a1r);
            ai[i] = fmaf(c, a0i, -s * a1i);
            ar[j] = fmaf(s, a0r,  c * a1r);
            ai[j] = fmaf(s, a0i,  c * a1i);
          }
        }
      }
#pragma unroll
      for (int i = 0; i < DIM; ++i) {
        ur[f * 256 + col * 16 + i] = ar[i];
        ui[f * 256 + col * 16 + i] = ai[i];
      }
    }
    __syncthreads();
    if (tid < NF * DIM) {
      const int k = col;
      const int pk = permf(k);
      const float* cr = ur + f * 256;
      const float* ci = ui + f * 256;
      float* dst = ws + f * 256 + k * 16;  // row k of M[f]
#pragma unroll
      for (int j = 0; j < DIM; ++j) {
        const int pj = permf(j);
        float acc = 0.f;
#pragma unroll
        for (int i = 0; i < DIM; ++i) {
          const float z = 1.f - 0.5f * (float)__popc(i);
          acc += z * (cr[pk * 16 + i] * cr[pj * 16 + i] +
                      ci[pk * 16 + i] * ci[pj * 16 + i]);
        }
        dst[j] = acc;
      }
    }
  } else {
    const int n = blockIdx.x * 256 + tid;
    if (n >= NPIX) return;
    const int b = n / (OH * OW);
    const int rem = n - b * (OH * OW);
    const int oi = rem / OW;
    const int oj = rem - oi * OW;

    const float* base = x + (((b * H) + oi) * W + oj) * CH;
    float ss = 0.f;
    float4 f0 = make_float4(0.f, 0.f, 0.f, 0.f);
#pragma unroll
    for (int fi = 0; fi < 2; ++fi) {
      const float4* row = reinterpret_cast<const float4*>(base + fi * W * CH);
#pragma unroll
      for (int k = 0; k < 8; ++k) {
        const float4 v = row[k];
        if (fi == 0 && k == 0) f0 = v;
        ss = fmaf(v.x, v.x, ss); ss = fmaf(v.y, v.y, ss);
        ss = fmaf(v.z, v.z, ss); ss = fmaf(v.w, v.w, ss);
      }
    }
    const float inv = rsqrtf(fmaxf(ss, 1e-12f));

    float cq[4], sq[4];
    __sincosf(f0.x * inv * 0.5f, &sq[0], &cq[0]);
    __sincosf(f0.y * inv * 0.5f, &sq[1], &cq[1]);
    __sincosf(f0.z * inv * 0.5f, &sq[2], &cq[2]);
    __sincosf(f0.w * inv * 0.5f, &sq[3], &cq[3]);

    float st[DIM];
#pragma unroll
    for (int i = 0; i < DIM; ++i) {
      st[i] = ((i & 8) ? sq[0] : cq[0]) * ((i & 4) ? sq[1] : cq[1]) *
              ((i & 2) ? sq[2] : cq[2]) * ((i & 1) ? sq[3] : cq[3]);
    }
    float4* dst = reinterpret_cast<float4*>(ws + PSI_OFF + n * 16);
    dst[0] = make_float4(st[0], st[1], st[2], st[3]);
    dst[1] = make_float4(st[4], st[5], st[6], st[7]);
    dst[2] = make_float4(st[8], st[9], st[10], st[11]);
    dst[3] = make_float4(st[12], st[13], st[14], st[15]);
  }
}

// K2: out[n,f] = psi_n^T M_f psi_n.
// Block = 512 threads = 8 waves; wave w -> filter w (wave-uniform => M rows via s_load).
// Each lane handles 2 patches. LDS transpose for coalesced stores.
__global__ __launch_bounds__(512)
void apply_kernel(const float* __restrict__ ws, float* __restrict__ out) {
  __shared__ float os[PPB * 9];  // [p][f] padded stride 9 -> conflict-free
  const int tid = threadIdx.x;
  const int lane = tid & 63;
  const int f = __builtin_amdgcn_readfirstlane(tid >> 6);  // wave-uniform SGPR
  const float* __restrict__ M = ws + f * 256;              // uniform -> s_load
  const int pbase = blockIdx.x * PPB;

  const int n0 = pbase + lane;
  const int n1 = pbase + 64 + lane;
  const int c0 = n0 < NPIX ? n0 : NPIX - 1;
  const int c1 = n1 < NPIX ? n1 : NPIX - 1;

  float pa[DIM], pb[DIM];
  {
    const float4* p0 = reinterpret_cast<const float4*>(ws + PSI_OFF + c0 * 16);
    const float4 a0 = p0[0], a1 = p0[1], a2 = p0[2], a3 = p0[3];
    pa[0] = a0.x;  pa[1] = a0.y;  pa[2] = a0.z;  pa[3] = a0.w;
    pa[4] = a1.x;  pa[5] = a1.y;  pa[6] = a1.z;  pa[7] = a1.w;
    pa[8] = a2.x;  pa[9] = a2.y;  pa[10] = a2.z; pa[11] = a2.w;
    pa[12] = a3.x; pa[13] = a3.y; pa[14] = a3.z; pa[15] = a3.w;
    const float4* p1 = reinterpret_cast<const float4*>(ws + PSI_OFF + c1 * 16);
    const float4 b0 = p1[0], b1 = p1[1], b2 = p1[2], b3 = p1[3];
    pb[0] = b0.x;  pb[1] = b0.y;  pb[2] = b0.z;  pb[3] = b0.w;
    pb[4] = b1.x;  pb[5] = b1.y;  pb[6] = b1.z;  pb[7] = b1.w;
    pb[8] = b2.x;  pb[9] = b2.y;  pb[10] = b2.z; pb[11] = b2.w;
    pb[12] = b3.x; pb[13] = b3.y; pb[14] = b3.z; pb[15] = b3.w;
  }

  float ya[DIM], yb[DIM];
#pragma unroll
  for (int i = 0; i < DIM; ++i) { ya[i] = 0.f; yb[i] = 0.f; }

#pragma unroll
  for (int k = 0; k < DIM; ++k) {
    const float ak = pa[k];
    const float bk = pb[k];
#pragma unroll
    for (int j = 0; j < DIM; ++j) {
      const float m = M[k * 16 + j];  // SGPR (wave-uniform)
      ya[j] = fmaf(m, ak, ya[j]);
      yb[j] = fmaf(m, bk, yb[j]);
    }
  }

  float a0 = 0.f, a1 = 0.f, a2 = 0.f, a3 = 0.f;
  float b0 = 0.f, b1 = 0.f, b2 = 0.f, b3 = 0.f;
#pragma unroll
  for (int i = 0; i < DIM; i += 4) {
    a0 = fmaf(pa[i + 0], ya[i + 0], a0);
    a1 = fmaf(pa[i + 1], ya[i + 1], a1);
    a2 = fmaf(pa[i + 2], ya[i + 2], a2);
    a3 = fmaf(pa[i + 3], ya[i + 3], a3);
    b0 = fmaf(pb[i + 0], yb[i + 0], b0);
    b1 = fmaf(pb[i + 1], yb[i + 1], b1);
    b2 = fmaf(pb[i + 2], yb[i + 2], b2);
    b3 = fmaf(pb[i + 3], yb[i + 3], b3);
  }
  os[lane * 9 + f] = (a0 + a1) + (a2 + a3);
  os[(64 + lane) * 9 + f] = (b0 + b1) + (b2 + b3);
  __syncthreads();

  // 1024 outputs, 512 threads x float2, coalesced
  const int j2 = tid * 2;
  const int p = j2 >> 3;
  const int e = j2 & 7;
  const long gi = (long)pbase * 8 + j2;
  if (gi + 1 < (long)NPIX * 8) {
    const float v0 = os[p * 9 + e];
    const float v1 = os[p * 9 + e + 1];
    *reinterpret_cast<float2*>(out + gi) = make_float2(v0, v1);
  }
}

extern "C" void kernel_launch(void* const* d_in, const int* in_sizes, int n_in,
                              void* d_out, int out_size, void* d_ws, size_t ws_size,
                              hipStream_t stream) {
  const float* x = (const float*)d_in[0];
  const float* w = (const float*)d_in[1];
  float* out = (float*)d_out;
  float* ws = (float*)d_ws;

  prep_kernel<<<dim3(PSIBLK + 1), dim3(256), 0, stream>>>(x, w, ws);
  apply_kernel<<<dim3(ABLK), dim3(512), 0, stream>>>(ws, out);
}

// Round 7
// 69.275 us; speedup vs baseline: 1.2382x; 1.1057x over previous
//
#include <hip/hip_runtime.h>

namespace {
constexpr int DIM = 16;
constexpr int BATCH = 8;
constexpr int H = 96, W = 96, CH = 16;
constexpr int OH = 95, OW = 95;
constexpr int NF = 8, NW = 24;
constexpr int NPIX = BATCH * OH * OW;          // 72200
constexpr int PPB = 128;                       // patches per block
constexpr int ABLK = (NPIX + PPB - 1) / PPB;   // 565
}

__device__ __forceinline__ int permf(int i) {
  int j = i;
  if (j & 8) j ^= 4;
  if (j & 4) j ^= 2;
  if (j & 2) j ^= 1;
  return j;
}

// ---- K1: 8 blocks (one per filter) x 256 threads -> M_f = perm(Re(U^H Z U)) ----
__global__ __launch_bounds__(256)
void build_m_kernel(const float* __restrict__ wts, float* __restrict__ ws) {
  __shared__ float ur[DIM * 17];
  __shared__ float ui[DIM * 17];
  const int f = blockIdx.x;
  const int tid = threadIdx.x;

  if (tid < DIM) {
    const int col = tid;
    const float* w = wts + f * NW;
    float ar[DIM], ai[DIM];
#pragma unroll
    for (int i = 0; i < DIM; ++i) { ar[i] = (i == col) ? 1.f : 0.f; ai[i] = 0.f; }
#pragma unroll
    for (int layer = 0; layer < 2; ++layer) {
      const int wb = layer * 12;
#pragma unroll
      for (int q = 0; q < 4; ++q) {
        const int m = 8 >> q;
        float c, s;
        {  // RX
          __sincosf(w[wb + q * 3] * 0.5f, &s, &c);
#pragma unroll
          for (int i = 0; i < DIM; ++i) {
            if (i & m) continue;
            const int j = i | m;
            const float a0r = ar[i], a0i = ai[i], a1r = ar[j], a1i = ai[j];
            ar[i] = fmaf(c, a0r,  s * a1i);
            ai[i] = fmaf(c, a0i, -s * a1r);
            ar[j] = fmaf(c, a1r,  s * a0i);
            ai[j] = fmaf(c, a1i, -s * a0r);
          }
        }
        {  // RY
          __sincosf(w[wb + q * 3 + 1] * 0.5f, &s, &c);
#pragma unroll
          for (int i = 0; i < DIM; ++i) {
            if (i & m) continue;
            const int j = i | m;
            const float a0r = ar[i], a0i = ai[i], a1r = ar[j], a1i = ai[j];
            ar[i] = fmaf(c, a0r, -s * a1r);
            ai[i] = fmaf(c, a0i, -s * a1i);
            ar[j] = fmaf(s, a0r,  c * a1r);
            ai[j] = fmaf(s, a0i,  c * a1i);
          }
        }
        {  // RZ
          __sincosf(w[wb + q * 3 + 2] * 0.5f, &s, &c);
#pragma unroll
          for (int i = 0; i < DIM; ++i) {
            const float r = ar[i], im = ai[i];
            if (i & m) { ar[i] = fmaf(c, r, -s * im); ai[i] = fmaf(c, im,  s * r); }
            else       { ar[i] = fmaf(c, r,  s * im); ai[i] = fmaf(c, im, -s * r); }
          }
        }
      }
      {  // CRY(ctrl bit8, tgt bit4)
        float c, s;
        __sincosf(w[wb + 0] * 0.5f, &s, &c);
#pragma unroll
        for (int i = 0; i < DIM; ++i) {
          if (!(i & 8) || (i & 4)) continue;
          const int j = i | 4;
          const float a0r = ar[i], a0i = ai[i], a1r = ar[j], a1i = ai[j];
          ar[i] = fmaf(c, a0r, -s * a1r);
          ai[i] = fmaf(c, a0i, -s * a1i);
          ar[j] = fmaf(s, a0r,  c * a1r);
          ai[j] = fmaf(s, a0i,  c * a1i);
        }
      }
      {  // CRY(ctrl bit2, tgt bit1)
        float c, s;
        __sincosf(w[wb + 2] * 0.5f, &s, &c);
#pragma unroll
        for (int i = 0; i < DIM; ++i) {
          if (!(i & 2) || (i & 1)) continue;
          const int j = i | 1;
          const float a0r = ar[i], a0i = ai[i], a1r = ar[j], a1i = ai[j];
          ar[i] = fmaf(c, a0r, -s * a1r);
          ai[i] = fmaf(c, a0i, -s * a1i);
          ar[j] = fmaf(s, a0r,  c * a1r);
          ai[j] = fmaf(s, a0i,  c * a1i);
        }
      }
    }
    // ur[i][col] = U_{i,col}, stride-17 pad
#pragma unroll
    for (int i = 0; i < DIM; ++i) {
      ur[i * 17 + col] = ar[i];
      ui[i * 17 + col] = ai[i];
    }
  }
  __syncthreads();

  // thread (k,j): M[k][j] = sum_i z_i (U[i,pk]U[i,pj] + Ui[i,pk]Ui[i,pj])
  const int k = tid >> 4;
  const int j = tid & 15;
  const int pk = permf(k);
  const int pj = permf(j);
  float acc = 0.f;
#pragma unroll
  for (int i = 0; i < DIM; ++i) {
    const float z = 1.f - 0.5f * (float)__popc(i);
    acc = fmaf(z * ur[i * 17 + pk], ur[i * 17 + pj], acc);
    acc = fmaf(z * ui[i * 17 + pk], ui[i * 17 + pj], acc);
  }
  ws[f * 256 + k * 16 + j] = acc;  // coalesced
}

// ---- K2: fused psi + quadratic form. 565 blocks x 512 threads (8 waves). ----
// Phase A: threads 0-127 compute psi for the block's 128 patches -> LDS (stride 17);
//          threads 128-383 stage M (2048 floats) -> LDS.
// Phase B: wave w = filter w (readfirstlane -> SGPR); lane handles 2 patches;
//          M rows read wave-uniform (ds_read_b128 broadcast, conflict-free).
// Stores via LDS transpose (stride 9), fully coalesced float2.
__global__ __launch_bounds__(512)
void fused_kernel(const float* __restrict__ x, const float* __restrict__ ws,
                  float* __restrict__ out) {
  __shared__ float Ml[NF * 256];     // 8 KB
  __shared__ float psis[PPB * 17];   // 8.7 KB
  __shared__ float os[PPB * 9];      // 4.6 KB
  const int tid = threadIdx.x;
  const int pbase = blockIdx.x * PPB;

  if (tid < PPB) {
    int n = pbase + tid;
    if (n >= NPIX) n = NPIX - 1;
    const int b = n / (OH * OW);
    const int rem = n - b * (OH * OW);
    const int oi = rem / OW;
    const int oj = rem - oi * OW;

    const float* base = x + (((b * H) + oi) * W + oj) * CH;
    float ss = 0.f;
    float4 f0 = make_float4(0.f, 0.f, 0.f, 0.f);
#pragma unroll
    for (int fi = 0; fi < 2; ++fi) {
      const float4* row = reinterpret_cast<const float4*>(base + fi * W * CH);
#pragma unroll
      for (int k = 0; k < 8; ++k) {
        const float4 v = row[k];
        if (fi == 0 && k == 0) f0 = v;
        ss = fmaf(v.x, v.x, ss); ss = fmaf(v.y, v.y, ss);
        ss = fmaf(v.z, v.z, ss); ss = fmaf(v.w, v.w, ss);
      }
    }
    const float inv = rsqrtf(fmaxf(ss, 1e-12f));

    float cq[4], sq[4];
    __sincosf(f0.x * inv * 0.5f, &sq[0], &cq[0]);
    __sincosf(f0.y * inv * 0.5f, &sq[1], &cq[1]);
    __sincosf(f0.z * inv * 0.5f, &sq[2], &cq[2]);
    __sincosf(f0.w * inv * 0.5f, &sq[3], &cq[3]);

#pragma unroll
    for (int i = 0; i < DIM; ++i) {
      psis[tid * 17 + i] =
          ((i & 8) ? sq[0] : cq[0]) * ((i & 4) ? sq[1] : cq[1]) *
          ((i & 2) ? sq[2] : cq[2]) * ((i & 1) ? sq[3] : cq[3]);
    }
  } else if (tid < 384) {
    const int i = tid - 128;  // 0..255, two float4 each
    const float4* src = reinterpret_cast<const float4*>(ws);
    reinterpret_cast<float4*>(Ml)[i] = src[i];
    reinterpret_cast<float4*>(Ml)[i + 256] = src[i + 256];
  }
  __syncthreads();

  const int lane = tid & 63;
  const int f = __builtin_amdgcn_readfirstlane(tid >> 6);  // wave-uniform SGPR
  const float* Mrow = Ml + f * 256;

  float pa[DIM], pb[DIM];
#pragma unroll
  for (int k = 0; k < DIM; ++k) {
    pa[k] = psis[lane * 17 + k];
    pb[k] = psis[(64 + lane) * 17 + k];
  }

  float ya[DIM], yb[DIM];
#pragma unroll
  for (int i = 0; i < DIM; ++i) { ya[i] = 0.f; yb[i] = 0.f; }

#pragma unroll
  for (int k = 0; k < DIM; ++k) {
    const float ak = pa[k];
    const float bk = pb[k];
    const float4 m0 = *reinterpret_cast<const float4*>(Mrow + k * 16 + 0);
    const float4 m1 = *reinterpret_cast<const float4*>(Mrow + k * 16 + 4);
    const float4 m2 = *reinterpret_cast<const float4*>(Mrow + k * 16 + 8);
    const float4 m3 = *reinterpret_cast<const float4*>(Mrow + k * 16 + 12);
    ya[0]  = fmaf(m0.x, ak, ya[0]);  yb[0]  = fmaf(m0.x, bk, yb[0]);
    ya[1]  = fmaf(m0.y, ak, ya[1]);  yb[1]  = fmaf(m0.y, bk, yb[1]);
    ya[2]  = fmaf(m0.z, ak, ya[2]);  yb[2]  = fmaf(m0.z, bk, yb[2]);
    ya[3]  = fmaf(m0.w, ak, ya[3]);  yb[3]  = fmaf(m0.w, bk, yb[3]);
    ya[4]  = fmaf(m1.x, ak, ya[4]);  yb[4]  = fmaf(m1.x, bk, yb[4]);
    ya[5]  = fmaf(m1.y, ak, ya[5]);  yb[5]  = fmaf(m1.y, bk, yb[5]);
    ya[6]  = fmaf(m1.z, ak, ya[6]);  yb[6]  = fmaf(m1.z, bk, yb[6]);
    ya[7]  = fmaf(m1.w, ak, ya[7]);  yb[7]  = fmaf(m1.w, bk, yb[7]);
    ya[8]  = fmaf(m2.x, ak, ya[8]);  yb[8]  = fmaf(m2.x, bk, yb[8]);
    ya[9]  = fmaf(m2.y, ak, ya[9]);  yb[9]  = fmaf(m2.y, bk, yb[9]);
    ya[10] = fmaf(m2.z, ak, ya[10]); yb[10] = fmaf(m2.z, bk, yb[10]);
    ya[11] = fmaf(m2.w, ak, ya[11]); yb[11] = fmaf(m2.w, bk, yb[11]);
    ya[12] = fmaf(m3.x, ak, ya[12]); yb[12] = fmaf(m3.x, bk, yb[12]);
    ya[13] = fmaf(m3.y, ak, ya[13]); yb[13] = fmaf(m3.y, bk, yb[13]);
    ya[14] = fmaf(m3.z, ak, ya[14]); yb[14] = fmaf(m3.z, bk, yb[14]);
    ya[15] = fmaf(m3.w, ak, ya[15]); yb[15] = fmaf(m3.w, bk, yb[15]);
  }

  float a0 = 0.f, a1 = 0.f, a2 = 0.f, a3 = 0.f;
  float b0 = 0.f, b1 = 0.f, b2 = 0.f, b3 = 0.f;
#pragma unroll
  for (int i = 0; i < DIM; i += 4) {
    a0 = fmaf(pa[i + 0], ya[i + 0], a0);
    a1 = fmaf(pa[i + 1], ya[i + 1], a1);
    a2 = fmaf(pa[i + 2], ya[i + 2], a2);
    a3 = fmaf(pa[i + 3], ya[i + 3], a3);
    b0 = fmaf(pb[i + 0], yb[i + 0], b0);
    b1 = fmaf(pb[i + 1], yb[i + 1], b1);
    b2 = fmaf(pb[i + 2], yb[i + 2], b2);
    b3 = fmaf(pb[i + 3], yb[i + 3], b3);
  }
  os[lane * 9 + f] = (a0 + a1) + (a2 + a3);
  os[(64 + lane) * 9 + f] = (b0 + b1) + (b2 + b3);
  __syncthreads();

  // 1024 outputs per block, 512 threads x float2, coalesced
  const int j2 = tid * 2;
  const int p = j2 >> 3;
  const int e = j2 & 7;
  const long gi = (long)pbase * 8 + j2;
  if (gi + 1 < (long)NPIX * 8) {
    *reinterpret_cast<float2*>(out + gi) =
        make_float2(os[p * 9 + e], os[p * 9 + e + 1]);
  }
}

extern "C" void kernel_launch(void* const* d_in, const int* in_sizes, int n_in,
                              void* d_out, int out_size, void* d_ws, size_t ws_size,
                              hipStream_t stream) {
  const float* x = (const float*)d_in[0];
  const float* w = (const float*)d_in[1];
  float* out = (float*)d_out;
  float* ws = (float*)d_ws;

  build_m_kernel<<<dim3(NF), dim3(256), 0, stream>>>(w, ws);
  fused_kernel<<<dim3(ABLK), dim3(512), 0, stream>>>(x, ws, out);
}